// Round 7
// baseline (57.401 us; speedup 1.0000x reference)
//
#include <hip/hip_runtime.h>

#define DEV __device__ __forceinline__

typedef unsigned short u16;
typedef unsigned int u32;
typedef float f32x4 __attribute__((ext_vector_type(4)));
typedef float f32x16 __attribute__((ext_vector_type(16)));
typedef __bf16 b16x8 __attribute__((ext_vector_type(8)));
typedef u16 u16x8 __attribute__((ext_vector_type(8)));
typedef u16 u16x4 __attribute__((ext_vector_type(4)));
typedef u32 u32x4 __attribute__((ext_vector_type(4)));

// 1/sqrt(D) * log2(e): QK^T logits directly in log2 units (exp -> v_exp_f32)
#define QSCALE (0.08838834764831845f * 1.44269504089f)

DEV u16 bfr(float x) {  // fp32 -> bf16 RNE
  u32 u = __builtin_bit_cast(u32, x);
  u32 r = u + 0x7fffu + ((u >> 16) & 1u);
  return (u16)(r >> 16);
}

DEV f32x4 mfma16(b16x8 a, b16x8 b, f32x4 c) {
  return __builtin_amdgcn_mfma_f32_16x16x32_bf16(a, b, c, 0, 0, 0);
}

DEV void plswap(u32& a, u32& b) {  // a' = [a.lo32lanes, b.lo32lanes]; b' = [a.hi, b.hi]
  asm volatile("v_permlane32_swap_b32 %0, %1" : "+v"(a), "+v"(b));
}

DEV float fexp2(float x) {  // raw v_exp_f32: 2^x, no libm legalization
  float r;
  asm("v_exp_f32 %0, %1" : "=v"(r) : "v"(x));
  return r;
}

DEV void gll16(const void* g, void* l) {
  __builtin_amdgcn_global_load_lds((const __attribute__((address_space(1))) u32*)g,
                                   (__attribute__((address_space(3))) u32*)l, 16, 0, 0);
}
DEV void gll4(const void* g, void* l) {
  __builtin_amdgcn_global_load_lds((const __attribute__((address_space(1))) u32*)g,
                                   (__attribute__((address_space(3))) u32*)l, 4, 0, 0);
}

// ---------------------------------------------------------------------------
// K1: fused QKV projection + mask->f32 conversion.  grid (64, 3), 256 threads.
// mode 0: qp fp32 + q_bf (pre-scaled by QSCALE) [+ mask conv on blocks <32];
// mode 1: k_bf; mode 2: vt (transposed).   [EXACT round-5 proven source]
// ---------------------------------------------------------------------------
__global__ __launch_bounds__(256) void k_proj(
    const float* __restrict__ Xq, const float* __restrict__ Xk, const float* __restrict__ Xv,
    const float* __restrict__ Wq, const float* __restrict__ Wk, const float* __restrict__ Wv,
    const float* __restrict__ bq, const float* __restrict__ bk, const float* __restrict__ bv,
    const int* __restrict__ mask, float* __restrict__ mf,
    float* __restrict__ qp, u16* __restrict__ q_bf, u16* __restrict__ k_bf,
    u16* __restrict__ vt) {
  __shared__ __align__(16) u16 Xs[128 * 128];
  __shared__ __align__(16) u16 Ws[128 * 128];
  const int tid = threadIdx.x;
  const int mode = blockIdx.y;
  const float* X = (mode == 0) ? Xq : (mode == 1 ? Xk : Xv);
  const float* W = (mode == 0) ? Wq : (mode == 1 ? Wk : Wv);
  const float* bias = (mode == 0) ? bq : (mode == 1 ? bk : bv);
  const int row0 = blockIdx.x * 128;
  char* xb = (char*)Xs;
  char* wb = (char*)Ws;

  if (mode == 0 && blockIdx.x < 32) {  // folded k_maskf
    int i = blockIdx.x * 256 + tid;
    mf[i] = mask[i] ? 0.f : -1e30f;
  }

#pragma unroll
  for (int i = 0; i < 8; ++i) {
    int s = tid + i * 256;
    int row = s >> 4;
    int c0 = (s & 15) * 8;
    const float* src = X + (size_t)(row0 + row) * 128 + c0;
    float4 f0 = *(const float4*)src;
    float4 f1 = *(const float4*)(src + 4);
    u16x8 hv;
    hv[0] = bfr(f0.x); hv[1] = bfr(f0.y); hv[2] = bfr(f0.z); hv[3] = bfr(f0.w);
    hv[4] = bfr(f1.x); hv[5] = bfr(f1.y); hv[6] = bfr(f1.z); hv[7] = bfr(f1.w);
    *(u16x8*)(xb + ((s * 16) ^ ((row & 7) << 4))) = hv;
  }
#pragma unroll
  for (int i = 0; i < 16; ++i) {
    int vecid = i * 256 + tid;
    int kk = vecid >> 5;
    int n0 = (vecid & 31) * 4;
    float4 f = *(const float4*)(W + (size_t)kk * 128 + n0);
    float ff[4] = {f.x, f.y, f.z, f.w};
#pragma unroll
    for (int j = 0; j < 4; ++j) {
      int n = n0 + j;
      *(u16*)(wb + ((n * 256 + kk * 2) ^ ((n & 7) << 4))) = bfr(ff[j]);
    }
  }
  __syncthreads();

  const int lane = tid & 63, wid = tid >> 6;
  const int g = lane >> 4, c = lane & 15;
  const int wi = wid >> 1, wj = wid & 1;

  f32x4 acc[4][4];
#pragma unroll
  for (int a = 0; a < 4; ++a)
#pragma unroll
    for (int b2 = 0; b2 < 4; ++b2) acc[a][b2] = f32x4{0.f, 0.f, 0.f, 0.f};

#pragma unroll
  for (int kk = 0; kk < 4; ++kk) {
    b16x8 af[4], bfv[4];
#pragma unroll
    for (int t = 0; t < 4; ++t) {
      int row = wi * 64 + t * 16 + c;
      af[t] = *(const b16x8*)(xb + ((row * 256 + kk * 64 + g * 16) ^ ((row & 7) << 4)));
      int col = wj * 64 + t * 16 + c;
      bfv[t] = *(const b16x8*)(wb + ((col * 256 + kk * 64 + g * 16) ^ ((col & 7) << 4)));
    }
#pragma unroll
    for (int ti = 0; ti < 4; ++ti)
#pragma unroll
      for (int tj = 0; tj < 4; ++tj) acc[ti][tj] = mfma16(af[ti], bfv[tj], acc[ti][tj]);
  }

#pragma unroll
  for (int tj = 0; tj < 4; ++tj) {
    int col = wj * 64 + tj * 16 + c;
    float bia = bias[col];
    int h = col >> 4, dh = col & 15;
#pragma unroll
    for (int ti = 0; ti < 4; ++ti) {
      int nbase = row0 + wi * 64 + ti * 16 + g * 4;
      f32x4 v4 = acc[ti][tj];
      if (mode == 2) {
        u16x4 pk;
#pragma unroll
        for (int r = 0; r < 4; ++r) pk[r] = bfr(v4[r] + bia);
        int bb2 = nbase >> 11, n = nbase & 2047;
        *(u16x4*)(vt + ((((size_t)bb2 * 8 + h) * 16 + dh) << 11) + n) = pk;
      } else {
        u16* dst = (mode == 0) ? q_bf : k_bf;
        float sc = (mode == 0) ? QSCALE : 1.0f;
#pragma unroll
        for (int r = 0; r < 4; ++r) {
          int rowg = nbase + r;
          float val = v4[r] + bia;
          if (mode == 0) qp[(size_t)rowg * 128 + col] = val;
          int bb2 = rowg >> 11, n = rowg & 2047;
          dst[((((size_t)bb2 * 8 + h) * 2048 + n) << 4) + dh] = bfr(val * sc);
        }
      }
    }
  }
}

// ---------------------------------------------------------------------------
// K2: flash attention, swapped-QK 32x32x16, mask-as-MFMA-C, MFMA row-sum.
// [EXACT round-5 proven source; only change: SPLIT 4 -> 8 (2 tile iters)]
// grid (NQ/128, B*H, SPLIT=8), 256 threads (4 waves x 32 q-rows).
// ---------------------------------------------------------------------------
__global__ __launch_bounds__(256) void k_attn5(
    const u16* __restrict__ q_bf, const u16* __restrict__ k_bf,
    const u16* __restrict__ vt, const float* __restrict__ mf,
    u16* __restrict__ OpartB, u16* __restrict__ LpartB) {
  __shared__ __align__(16) u16 Ks[2][128 * 16];    // [slot sigma] (16B slots)
  __shared__ __align__(16) u16 Vs[2][17 * 128];    // [dh][k] swizzled + ones row at dh=16
  __shared__ __align__(16) float Mf2[2][128];      // mask addends
  const int tid = threadIdx.x, lane = tid & 63, wid = tid >> 6;
  const int q = lane & 31, h = lane >> 5;
  const int bh = blockIdx.y, b = bh >> 3;
  const int z = blockIdx.z;
  const int q0 = blockIdx.x * 128 + wid * 32;

  const u16* Kg = k_bf + (size_t)bh * 2048 * 16;
  const u16* Vg = vt + (size_t)bh * 16 * 2048;
  const float* Mg = mf + (size_t)b * 2048;

  // Q B-fragment (col=q, k=dh): in regs all kernel
  b16x8 qf = *(const b16x8*)(q_bf + (((size_t)bh * 2048 + q0 + q) << 4) + h * 8);

  // ones rows (dh=16) for both buffers: rowsum-by-MFMA column
  if (tid < 32) {
    u16x8 ov;
#pragma unroll
    for (int i = 0; i < 8; ++i) ov[i] = 0x3F80;  // bf16 1.0
    *(u16x8*)(&Vs[tid >> 4][16 * 128 + (tid & 15) * 8]) = ov;
  }

  f32x16 oacc = {};

  auto stage = [&](int bufi, int ct2) {
    const int kt0 = ct2 * 128;
    // K: dest slot t linear; source slot sigma(t) (involution) -> swizzled LDS
    {
      const int t = wid * 64 + lane;
      const int ssrc = t ^ ((t >> 3) & 7);
      gll16(Kg + (size_t)kt0 * 16 + ssrc * 8, &Ks[bufi][wid * 512]);
    }
    {
      const int dhs = wid * 4 + (lane >> 4);
      const int ts = (lane & 15) ^ (dhs & 7);
      gll16(Vg + (size_t)dhs * 2048 + kt0 + ts * 8, &Vs[bufi][wid * 512]);
    }
    if (wid < 2) gll4(Mg + kt0 + wid * 64 + lane, &Mf2[bufi][wid * 64]);
  };

  const int ct0 = z * 2;   // SPLIT=8: 2 x 128-key tiles per block
  stage(0, ct0);
  const int dhc = (q < 16) ? q : 16;  // V col: dh, clamped to ones row

  for (int ct = ct0; ct < ct0 + 2; ++ct) {
    const int cur = ct & 1;
    __syncthreads();
    if (ct < ct0 + 1) stage(cur ^ 1, ct + 1);
    const char* ksb = (const char*)Ks[cur];
    const char* vsb = (const char*)Vs[cur];
    const float* mfb = Mf2[cur];

#pragma unroll
    for (int kt = 0; kt < 4; ++kt) {
      // K A-fragment from sigma-swizzled slots
      const int s = kt * 64 + q * 2 + h;
      const int srd = s ^ ((s >> 3) & 7);
      b16x8 kf = *(const b16x8*)(ksb + srd * 16);

      // mask addends as MFMA C-input: C[r] = mf[key=(r&3)+8*(r>>2)+4h]
      const float* mrow = mfb + kt * 32 + 4 * h;
      f32x4 ma0 = *(const f32x4*)(mrow);
      f32x4 ma1 = *(const f32x4*)(mrow + 8);
      f32x4 ma2 = *(const f32x4*)(mrow + 16);
      f32x4 ma3 = *(const f32x4*)(mrow + 24);
      f32x16 cc;
#pragma unroll
      for (int j = 0; j < 4; ++j) {
        cc[j] = ma0[j]; cc[4 + j] = ma1[j]; cc[8 + j] = ma2[j]; cc[12 + j] = ma3[j];
      }
      // S^T + mask = mfma(A=K, B=Q, C=mask); lane: col=q, rows=keys
      f32x16 st = __builtin_amdgcn_mfma_f32_32x32x16_bf16(kf, qf, cc, 0, 0, 0);

      // fixed-max softmax: p = 2^(st); masked -> v_exp(-1e30) = 0
      float p[16];
#pragma unroll
      for (int r = 0; r < 16; ++r) p[r] = fexp2(st[r]);

      // T12: P -> bf16 PV A-fragments in-register
      u32 w[8];
#pragma unroll
      for (int i = 0; i < 8; ++i)
        asm("v_cvt_pk_bf16_f32 %0, %1, %2" : "=v"(w[i]) : "v"(p[2 * i]), "v"(p[2 * i + 1]));
      plswap(w[0], w[2]); plswap(w[1], w[3]);
      plswap(w[4], w[6]); plswap(w[5], w[7]);
      u32x4 f0v = {w[0], w[1], w[2], w[3]};
      u32x4 f1v = {w[4], w[5], w[6], w[7]};
      b16x8 F0 = __builtin_bit_cast(b16x8, f0v);
      b16x8 F1 = __builtin_bit_cast(b16x8, f1v);

      // V B-fragments (col=dh or ones row), swizzled slots
      const int t0 = (kt * 4 + h) ^ (dhc & 7);
      const int t1 = (kt * 4 + 2 + h) ^ (dhc & 7);
      b16x8 vf0 = *(const b16x8*)(vsb + (dhc * 16 + t0) * 16);
      b16x8 vf1 = *(const b16x8*)(vsb + (dhc * 16 + t1) * 16);
      oacc = __builtin_amdgcn_mfma_f32_32x32x16_bf16(F0, vf0, oacc, 0, 0, 0);
      oacc = __builtin_amdgcn_mfma_f32_32x32x16_bf16(F1, vf1, oacc, 0, 0, 0);
    }
  }

  // epilogue: cols 0-15 = un-normalized O (bf16); col 16 = l (bf16)
  const size_t rowbase = (size_t)(z * 32 + bh) * 2048 + q0;
  if (q < 16) {
    u16* op = OpartB + rowbase * 16 + q;
#pragma unroll
    for (int g2 = 0; g2 < 4; ++g2)
#pragma unroll
      for (int j = 0; j < 4; ++j) {
        int row = j + 8 * g2 + 4 * h;
        op[(size_t)row * 16] = bfr(oacc[g2 * 4 + j]);
      }
  } else if (q == 16) {
    u16* lp = LpartB + rowbase;
#pragma unroll
    for (int r = 0; r < 16; ++r) {
      int row = (r & 3) + 8 * (r >> 2) + 4 * h;
      lp[row] = bfr(oacc[r]);
    }
  }
}

// ---------------------------------------------------------------------------
// K3: fused tail: combine 8 partials + LN1 -> MLP GEMM -> relu+res -> LN2.
// grid 256 blocks x 32 rows, 256 threads (4 waves).  LDS 72KB -> 2 blk/CU.
// ---------------------------------------------------------------------------
__global__ __launch_bounds__(256) void k_tail(
    const float* __restrict__ qp, const u16* __restrict__ OpartB,
    const u16* __restrict__ LpartB,
    const float* __restrict__ g1, const float* __restrict__ b1,
    const float* __restrict__ Wo, const float* __restrict__ bo,
    const float* __restrict__ g2, const float* __restrict__ b2,
    float* __restrict__ out) {
  __shared__ __align__(16) u16 Ws[128 * 128];   // Wo^T bf16 swizzled (32KB)
  __shared__ __align__(16) u16 Xs[32 * 128];    // out1 bf16 swizzled (8KB)
  __shared__ __align__(16) float Xf[32 * 128];  // out1 f32, row-XOR (16KB)
  __shared__ __align__(16) float Yf[32 * 128];  // y f32, row-XOR (16KB)
  const int tid = threadIdx.x, lane = tid & 63, wid = tid >> 6;
  char* wb = (char*)Ws;
  char* xb = (char*)Xs;
  char* xfb = (char*)Xf;
  char* yfb = (char*)Yf;
  const int rows0 = blockIdx.x * 32;
  const int b = rows0 >> 11, n0 = rows0 & 2047;

  // --- stage Wo^T bf16 swizzled ---
#pragma unroll
  for (int i = 0; i < 16; ++i) {
    int vecid = i * 256 + tid;
    int kk = vecid >> 5;
    int nn = (vecid & 31) * 4;
    float4 f = *(const float4*)(Wo + (size_t)kk * 128 + nn);
    float ff[4] = {f.x, f.y, f.z, f.w};
#pragma unroll
    for (int j = 0; j < 4; ++j) {
      int n = nn + j;
      *(u16*)(wb + ((n * 256 + kk * 2) ^ ((n & 7) << 4))) = bfr(ff[j]);
    }
  }

  // --- phase A: combine partials + LN1; wave wid owns rows wid*8..+7 ---
  const int head = lane >> 3, dh = (lane & 7) * 2;
  const size_t SPLIT_O = (size_t)32 * 2048 * 16;
  const size_t SPLIT_L = (size_t)32 * 2048;
  float2 gg1 = *(const float2*)(g1 + lane * 2);
  float2 be1 = *(const float2*)(b1 + lane * 2);
#pragma unroll
  for (int rr = 0; rr < 8; ++rr) {
    const int lr = wid * 8 + rr;
    const int rg = rows0 + lr;
    const size_t pb = (size_t)(b * 8 + head) * 2048 + (n0 + lr);
    float ox = 0.f, oy = 0.f, l = 0.f;
#pragma unroll
    for (int zz = 0; zz < 8; ++zz) {
      u32 w = *(const u32*)(OpartB + zz * SPLIT_O + pb * 16 + dh);
      ox += __builtin_bit_cast(float, w << 16);
      oy += __builtin_bit_cast(float, w & 0xffff0000u);
      l += __builtin_bit_cast(float, (u32)LpartB[zz * SPLIT_L + pb] << 16);
    }
    float inv = (l > 0.f) ? 1.0f / l : 0.f;
    float2 a = *(const float2*)(qp + (size_t)rg * 128 + lane * 2);
    float x0 = a.x + ox * inv, x1 = a.y + oy * inv;
    float sum = x0 + x1, sq = x0 * x0 + x1 * x1;
#pragma unroll
    for (int off = 1; off < 64; off <<= 1) {
      sum += __shfl_xor(sum, off);
      sq += __shfl_xor(sq, off);
    }
    float mu = sum * (1.f / 128.f);
    float rstd = rsqrtf(sq * (1.f / 128.f) - mu * mu + 1e-6f);
    float y0 = (x0 - mu) * rstd * gg1.x + be1.x;
    float y1 = (x1 - mu) * rstd * gg1.y + be1.y;
    *(float2*)(xfb + (((lr * 512 + lane * 8)) ^ ((lr & 7) << 4))) = make_float2(y0, y1);
    *(u32*)(xb + ((lr * 256 + lane * 4) ^ ((lr & 7) << 4))) =
        (u32)bfr(y0) | ((u32)bfr(y1) << 16);
  }
  __syncthreads();

  // --- phase B: GEMM out1 @ Wo + relu + residual -> Yf ---
  const int g = lane >> 4, c = lane & 15;
  const int wi = wid >> 1, wj = wid & 1;
  f32x4 acc[4];
#pragma unroll
  for (int t = 0; t < 4; ++t) acc[t] = f32x4{0.f, 0.f, 0.f, 0.f};
#pragma unroll
  for (int kk = 0; kk < 4; ++kk) {
    const int row = wi * 16 + c;
    b16x8 af = *(const b16x8*)(xb + ((row * 256 + kk * 64 + g * 16) ^ ((row & 7) << 4)));
#pragma unroll
    for (int t = 0; t < 4; ++t) {
      int col = wj * 64 + t * 16 + c;
      b16x8 bfv = *(const b16x8*)(wb + ((col * 256 + kk * 64 + g * 16) ^ ((col & 7) << 4)));
      acc[t] = mfma16(af, bfv, acc[t]);
    }
  }
#pragma unroll
  for (int t = 0; t < 4; ++t) {
    const int col = wj * 64 + t * 16 + c;
    const float bia = bo[col];
#pragma unroll
    for (int r = 0; r < 4; ++r) {
      const int lr = wi * 16 + g * 4 + r;
      float o1 = *(const float*)(xfb + ((lr * 512 + col * 4) ^ ((lr & 7) << 4)));
      float val = fmaxf(acc[t][r] + bia, 0.f) + o1;
      *(float*)(yfb + ((lr * 512 + col * 4) ^ ((lr & 7) << 4))) = val;
    }
  }
  __syncthreads();

  // --- phase C: LN2 -> out ---
  float2 gg2 = *(const float2*)(g2 + lane * 2);
  float2 be2 = *(const float2*)(b2 + lane * 2);
#pragma unroll
  for (int rr = 0; rr < 8; ++rr) {
    const int lr = wid * 8 + rr;
    float2 a = *(const float2*)(yfb + ((lr * 512 + lane * 8) ^ ((lr & 7) << 4)));
    float x0 = a.x, x1 = a.y;
    float sum = x0 + x1, sq = x0 * x0 + x1 * x1;
#pragma unroll
    for (int off = 1; off < 64; off <<= 1) {
      sum += __shfl_xor(sum, off);
      sq += __shfl_xor(sq, off);
    }
    float mu = sum * (1.f / 128.f);
    float rstd = rsqrtf(sq * (1.f / 128.f) - mu * mu + 1e-6f);
    *(float2*)(out + (size_t)(rows0 + lr) * 128 + lane * 2) =
        make_float2((x0 - mu) * rstd * gg2.x + be2.x, (x1 - mu) * rstd * gg2.y + be2.y);
  }
}

// ---------------------------------------------------------------------------
extern "C" void kernel_launch(void* const* d_in, const int* in_sizes, int n_in,
                              void* d_out, int out_size, void* d_ws, size_t ws_size,
                              hipStream_t stream) {
  const float* q = (const float*)d_in[0];
  const float* k = (const float*)d_in[1];
  const float* v = (const float*)d_in[2];
  const int* mask = (const int*)d_in[3];
  const float* Wq = (const float*)d_in[4];
  const float* bq = (const float*)d_in[5];
  const float* Wk = (const float*)d_in[6];
  const float* bk = (const float*)d_in[7];
  const float* Wv = (const float*)d_in[8];
  const float* bv = (const float*)d_in[9];
  const float* Wo = (const float*)d_in[10];
  const float* bo = (const float*)d_in[11];
  const float* g1 = (const float*)d_in[12];
  const float* b1 = (const float*)d_in[13];
  const float* g2 = (const float*)d_in[14];
  const float* b2 = (const float*)d_in[15];

  // ws layout (~27 MiB high-water; ws is 256 MiB per harness poison size):
  char* ws = (char*)d_ws;
  float* qp = (float*)(ws + (0ull << 20));       // 0-4 MiB fp32 [8192][128]
  u16* q_bf = (u16*)(ws + (4ull << 20));         // 4-6 MiB [bh][n][16]
  u16* k_bf = (u16*)(ws + (6ull << 20));         // 6-8 MiB [bh][n][16]
  u16* vt = (u16*)(ws + (8ull << 20));           // 8-10 MiB [bh][16][2048]
  u16* OpartB = (u16*)(ws + (10ull << 20));      // 10-26 MiB [8][32][2048][16] bf16
  u16* LpartB = (u16*)(ws + (26ull << 20));      // 26-27 MiB [8][32][2048] bf16
  float* mf = (float*)(ws + (27ull << 20));      // 27-27.03 [B][2048]

  k_proj<<<dim3(64, 3), 256, 0, stream>>>(q, k, v, Wq, Wk, Wv, bq, bk, bv,
                                          mask, mf, qp, q_bf, k_bf, vt);
  k_attn5<<<dim3(16, 32, 8), 256, 0, stream>>>(q_bf, k_bf, vt, mf, OpartB, LpartB);
  k_tail<<<256, 256, 0, stream>>>(qp, OpartB, LpartB, g1, b1, Wo, bo, g2, b2,
                                  (float*)d_out);
}

// Round 8
// 55.498 us; speedup vs baseline: 1.0343x; 1.0343x over previous
//
#include <hip/hip_runtime.h>

#define DEV __device__ __forceinline__

typedef unsigned short u16;
typedef unsigned int u32;
typedef float f32x4 __attribute__((ext_vector_type(4)));
typedef float f32x16 __attribute__((ext_vector_type(16)));
typedef __bf16 b16x8 __attribute__((ext_vector_type(8)));
typedef u16 u16x8 __attribute__((ext_vector_type(8)));
typedef u16 u16x4 __attribute__((ext_vector_type(4)));
typedef u32 u32x4 __attribute__((ext_vector_type(4)));

// 1/sqrt(D) * log2(e): QK^T logits directly in log2 units (exp -> v_exp_f32)
#define QSCALE (0.08838834764831845f * 1.44269504089f)

DEV u16 bfr(float x) {  // fp32 -> bf16 RNE
  u32 u = __builtin_bit_cast(u32, x);
  u32 r = u + 0x7fffu + ((u >> 16) & 1u);
  return (u16)(r >> 16);
}

DEV f32x4 mfma16(b16x8 a, b16x8 b, f32x4 c) {
  return __builtin_amdgcn_mfma_f32_16x16x32_bf16(a, b, c, 0, 0, 0);
}

DEV void plswap(u32& a, u32& b) {  // a' = [a.lo32lanes, b.lo32lanes]; b' = [a.hi, b.hi]
  asm volatile("v_permlane32_swap_b32 %0, %1" : "+v"(a), "+v"(b));
}

DEV float fexp2(float x) {  // raw v_exp_f32: 2^x, no libm legalization
  float r;
  asm("v_exp_f32 %0, %1" : "=v"(r) : "v"(x));
  return r;
}

DEV void gll16(const void* g, void* l) {
  __builtin_amdgcn_global_load_lds((const __attribute__((address_space(1))) u32*)g,
                                   (__attribute__((address_space(3))) u32*)l, 16, 0, 0);
}
DEV void gll4(const void* g, void* l) {
  __builtin_amdgcn_global_load_lds((const __attribute__((address_space(1))) u32*)g,
                                   (__attribute__((address_space(3))) u32*)l, 4, 0, 0);
}

// ---------------------------------------------------------------------------
// K1: fused QKV projection + mask->bf16 0/1 conversion.  grid (64, 3).
// mode 0: qp fp32 + q_bf (pre-scaled by QSCALE) [+ mask01 conv on blocks <32];
// mode 1: k_bf; mode 2: vt (transposed, V rows of masked keys zeroed).
// ---------------------------------------------------------------------------
__global__ __launch_bounds__(256) void k_proj(
    const float* __restrict__ Xq, const float* __restrict__ Xk, const float* __restrict__ Xv,
    const float* __restrict__ Wq, const float* __restrict__ Wk, const float* __restrict__ Wv,
    const float* __restrict__ bq, const float* __restrict__ bk, const float* __restrict__ bv,
    const int* __restrict__ mask, u16* __restrict__ m01,
    float* __restrict__ qp, u16* __restrict__ q_bf, u16* __restrict__ k_bf,
    u16* __restrict__ vt) {
  __shared__ __align__(16) u16 Xs[128 * 128];
  __shared__ __align__(16) u16 Ws[128 * 128];
  const int tid = threadIdx.x;
  const int mode = blockIdx.y;
  const float* X = (mode == 0) ? Xq : (mode == 1 ? Xk : Xv);
  const float* W = (mode == 0) ? Wq : (mode == 1 ? Wk : Wv);
  const float* bias = (mode == 0) ? bq : (mode == 1 ? bk : bv);
  const int row0 = blockIdx.x * 128;
  char* xb = (char*)Xs;
  char* wb = (char*)Ws;

  if (mode == 0 && blockIdx.x < 32) {  // mask -> bf16 0/1
    int i = blockIdx.x * 256 + tid;
    m01[i] = mask[i] ? 0x3F80 : 0;
  }

#pragma unroll
  for (int i = 0; i < 8; ++i) {
    int s = tid + i * 256;
    int row = s >> 4;
    int c0 = (s & 15) * 8;
    const float* src = X + (size_t)(row0 + row) * 128 + c0;
    float4 f0 = *(const float4*)src;
    float4 f1 = *(const float4*)(src + 4);
    u16x8 hv;
    hv[0] = bfr(f0.x); hv[1] = bfr(f0.y); hv[2] = bfr(f0.z); hv[3] = bfr(f0.w);
    hv[4] = bfr(f1.x); hv[5] = bfr(f1.y); hv[6] = bfr(f1.z); hv[7] = bfr(f1.w);
    *(u16x8*)(xb + ((s * 16) ^ ((row & 7) << 4))) = hv;
  }
#pragma unroll
  for (int i = 0; i < 16; ++i) {
    int vecid = i * 256 + tid;
    int kk = vecid >> 5;
    int n0 = (vecid & 31) * 4;
    float4 f = *(const float4*)(W + (size_t)kk * 128 + n0);
    float ff[4] = {f.x, f.y, f.z, f.w};
#pragma unroll
    for (int j = 0; j < 4; ++j) {
      int n = n0 + j;
      *(u16*)(wb + ((n * 256 + kk * 2) ^ ((n & 7) << 4))) = bfr(ff[j]);
    }
  }
  __syncthreads();

  const int lane = tid & 63, wid = tid >> 6;
  const int g = lane >> 4, c = lane & 15;
  const int wi = wid >> 1, wj = wid & 1;

  f32x4 acc[4][4];
#pragma unroll
  for (int a = 0; a < 4; ++a)
#pragma unroll
    for (int b2 = 0; b2 < 4; ++b2) acc[a][b2] = f32x4{0.f, 0.f, 0.f, 0.f};

#pragma unroll
  for (int kk = 0; kk < 4; ++kk) {
    b16x8 af[4], bfv[4];
#pragma unroll
    for (int t = 0; t < 4; ++t) {
      int row = wi * 64 + t * 16 + c;
      af[t] = *(const b16x8*)(xb + ((row * 256 + kk * 64 + g * 16) ^ ((row & 7) << 4)));
      int col = wj * 64 + t * 16 + c;
      bfv[t] = *(const b16x8*)(wb + ((col * 256 + kk * 64 + g * 16) ^ ((col & 7) << 4)));
    }
#pragma unroll
    for (int ti = 0; ti < 4; ++ti)
#pragma unroll
      for (int tj = 0; tj < 4; ++tj) acc[ti][tj] = mfma16(af[ti], bfv[tj], acc[ti][tj]);
  }

#pragma unroll
  for (int tj = 0; tj < 4; ++tj) {
    int col = wj * 64 + tj * 16 + c;
    float bia = bias[col];
    int h = col >> 4, dh = col & 15;
#pragma unroll
    for (int ti = 0; ti < 4; ++ti) {
      int nbase = row0 + wi * 64 + ti * 16 + g * 4;
      f32x4 v4 = acc[ti][tj];
      if (mode == 2) {
        // zero masked keys' V: mask folded into PV + l-weights (exact)
        int bb2 = nbase >> 11, n = nbase & 2047;
        u16x4 pk;
#pragma unroll
        for (int r = 0; r < 4; ++r) {
          float mm = mask[bb2 * 2048 + n + r] ? 1.f : 0.f;
          pk[r] = bfr((v4[r] + bia) * mm);
        }
        *(u16x4*)(vt + ((((size_t)bb2 * 8 + h) * 16 + dh) << 11) + n) = pk;
      } else {
        u16* dst = (mode == 0) ? q_bf : k_bf;
        float sc = (mode == 0) ? QSCALE : 1.0f;
#pragma unroll
        for (int r = 0; r < 4; ++r) {
          int rowg = nbase + r;
          float val = v4[r] + bia;
          if (mode == 0) qp[(size_t)rowg * 128 + col] = val;
          int bb2 = rowg >> 11, n = rowg & 2047;
          dst[((((size_t)bb2 * 8 + h) * 2048 + n) << 4) + dh] = bfr(val * sc);
        }
      }
    }
  }
}

// ---------------------------------------------------------------------------
// K2: flash attention, swapped-QK 32x32x16, mask-free inner loop (mask is
// baked into V + the l-weight row), MFMA row-sum.  grid (16, 32, SPLIT=4),
// 256 threads (4 waves x 32 q-rows).  3 LDS reads/subtile (was 7).
// ---------------------------------------------------------------------------
__global__ __launch_bounds__(256) void k_attn7(
    const u16* __restrict__ q_bf, const u16* __restrict__ k_bf,
    const u16* __restrict__ vt, const u16* __restrict__ m01,
    u16* __restrict__ OpartB, u16* __restrict__ LpartB) {
  __shared__ __align__(16) u16 Ks[2][128 * 16];    // [slot sigma] (16B slots)
  __shared__ __align__(16) u16 Vs[2][17 * 128];    // [dh][k] swizzled; row16 = mask01
  const int tid = threadIdx.x, lane = tid & 63, wid = tid >> 6;
  const int q = lane & 31, h = lane >> 5;
  const int bh = blockIdx.y, b = bh >> 3;
  const int z = blockIdx.z;
  const int q0 = blockIdx.x * 128 + wid * 32;

  const u16* Kg = k_bf + (size_t)bh * 2048 * 16;
  const u16* Vg = vt + (size_t)bh * 16 * 2048;
  const u16* M01g = m01 + (size_t)b * 2048;

  // Q B-fragment (col=q, k=dh): in regs all kernel
  b16x8 qf = *(const b16x8*)(q_bf + (((size_t)bh * 2048 + q0 + q) << 4) + h * 8);

  f32x16 oacc = {};

  auto stage = [&](int bufi, int ct2) {
    const int kt0 = ct2 * 128;
    // K: dest slot t linear; source slot sigma(t) (involution) -> swizzled LDS
    {
      const int t = wid * 64 + lane;
      const int ssrc = t ^ ((t >> 3) & 7);
      gll16(Kg + (size_t)kt0 * 16 + ssrc * 8, &Ks[bufi][wid * 512]);
    }
    {
      const int dhs = wid * 4 + (lane >> 4);
      const int ts = (lane & 15) ^ (dhs & 7);
      gll16(Vg + (size_t)dhs * 2048 + kt0 + ts * 8, &Vs[bufi][wid * 512]);
    }
    // l-weight row (row 16, unswizzled): mask01 for these 128 keys (256B)
    if (wid == 0) gll4(M01g + kt0 + lane * 2, &Vs[bufi][16 * 128]);
  };

  const int ct0 = z * 4;
  stage(0, ct0);
  const int dhc = (q < 16) ? q : 16;  // V col: dh, clamped to mask01 row

  for (int ct = ct0; ct < ct0 + 4; ++ct) {
    const int cur = ct & 1;
    __syncthreads();
    if (ct < ct0 + 3) stage(cur ^ 1, ct + 1);
    const char* ksb = (const char*)Ks[cur];
    const char* vsb = (const char*)Vs[cur];

#pragma unroll
    for (int kt = 0; kt < 4; ++kt) {
      // K A-fragment from sigma-swizzled slots
      const int s = kt * 64 + q * 2 + h;
      const int srd = s ^ ((s >> 3) & 7);
      b16x8 kf = *(const b16x8*)(ksb + srd * 16);

      // S^T = mfma(A=K, B=Q, C=0); lane: col=q, rows=keys
      f32x16 zz = {};
      f32x16 st = __builtin_amdgcn_mfma_f32_32x32x16_bf16(kf, qf, zz, 0, 0, 0);

      // unmasked softmax numerator: p = 2^st (mask lives in V / l-weights)
      float p[16];
#pragma unroll
      for (int r = 0; r < 16; ++r) p[r] = fexp2(st[r]);

      // T12: P -> bf16 PV A-fragments in-register
      u32 w[8];
#pragma unroll
      for (int i = 0; i < 8; ++i)
        asm("v_cvt_pk_bf16_f32 %0, %1, %2" : "=v"(w[i]) : "v"(p[2 * i]), "v"(p[2 * i + 1]));
      plswap(w[0], w[2]); plswap(w[1], w[3]);
      plswap(w[4], w[6]); plswap(w[5], w[7]);
      u32x4 f0v = {w[0], w[1], w[2], w[3]};
      u32x4 f1v = {w[4], w[5], w[6], w[7]};
      b16x8 F0 = __builtin_bit_cast(b16x8, f0v);
      b16x8 F1 = __builtin_bit_cast(b16x8, f1v);

      // V B-fragments (col=dh, or mask01 row for q>=16), swizzled slots
      const int t0 = (kt * 4 + h) ^ (dhc & 7);
      const int t1 = (kt * 4 + 2 + h) ^ (dhc & 7);
      b16x8 vf0 = *(const b16x8*)(vsb + (dhc * 16 + t0) * 16);
      b16x8 vf1 = *(const b16x8*)(vsb + (dhc * 16 + t1) * 16);
      oacc = __builtin_amdgcn_mfma_f32_32x32x16_bf16(F0, vf0, oacc, 0, 0, 0);
      oacc = __builtin_amdgcn_mfma_f32_32x32x16_bf16(F1, vf1, oacc, 0, 0, 0);
    }
  }

  // epilogue: cols 0-15 = un-normalized O (bf16); col 16 = l (bf16)
  const size_t rowbase = (size_t)(z * 32 + bh) * 2048 + q0;
  if (q < 16) {
    u16* op = OpartB + rowbase * 16 + q;
#pragma unroll
    for (int g2 = 0; g2 < 4; ++g2)
#pragma unroll
      for (int j = 0; j < 4; ++j) {
        int row = j + 8 * g2 + 4 * h;
        op[(size_t)row * 16] = bfr(oacc[g2 * 4 + j]);
      }
  } else if (q == 16) {
    u16* lp = LpartB + rowbase;
#pragma unroll
    for (int r = 0; r < 16; ++r) {
      int row = (r & 3) + 8 * (r >> 2) + 4 * h;
      lp[row] = bfr(oacc[r]);
    }
  }
}

// ---------------------------------------------------------------------------
// K3: fused tail: combine 4 partials + LN1 -> MLP GEMM -> relu+res -> LN2.
// grid 256 blocks x 32 rows, 256 threads (4 waves).  LDS 72KB -> 2 blk/CU.
// ---------------------------------------------------------------------------
__global__ __launch_bounds__(256) void k_tail(
    const float* __restrict__ qp, const u16* __restrict__ OpartB,
    const u16* __restrict__ LpartB,
    const float* __restrict__ g1, const float* __restrict__ b1,
    const float* __restrict__ Wo, const float* __restrict__ bo,
    const float* __restrict__ g2, const float* __restrict__ b2,
    float* __restrict__ out) {
  __shared__ __align__(16) u16 Ws[128 * 128];   // Wo^T bf16 swizzled (32KB)
  __shared__ __align__(16) u16 Xs[32 * 128];    // out1 bf16 swizzled (8KB)
  __shared__ __align__(16) float Xf[32 * 128];  // out1 f32, row-XOR (16KB)
  __shared__ __align__(16) float Yf[32 * 128];  // y f32, row-XOR (16KB)
  const int tid = threadIdx.x, lane = tid & 63, wid = tid >> 6;
  char* wb = (char*)Ws;
  char* xb = (char*)Xs;
  char* xfb = (char*)Xf;
  char* yfb = (char*)Yf;
  const int rows0 = blockIdx.x * 32;
  const int b = rows0 >> 11, n0 = rows0 & 2047;

  // --- stage Wo^T bf16 swizzled ---
#pragma unroll
  for (int i = 0; i < 16; ++i) {
    int vecid = i * 256 + tid;
    int kk = vecid >> 5;
    int nn = (vecid & 31) * 4;
    float4 f = *(const float4*)(Wo + (size_t)kk * 128 + nn);
    float ff[4] = {f.x, f.y, f.z, f.w};
#pragma unroll
    for (int j = 0; j < 4; ++j) {
      int n = nn + j;
      *(u16*)(wb + ((n * 256 + kk * 2) ^ ((n & 7) << 4))) = bfr(ff[j]);
    }
  }

  // --- phase A: combine partials + LN1; wave wid owns rows wid*8..+7 ---
  const int head = lane >> 3, dh = (lane & 7) * 2;
  const size_t SPLIT_O = (size_t)32 * 2048 * 16;
  const size_t SPLIT_L = (size_t)32 * 2048;
  float2 gg1 = *(const float2*)(g1 + lane * 2);
  float2 be1 = *(const float2*)(b1 + lane * 2);
#pragma unroll
  for (int rr = 0; rr < 8; ++rr) {
    const int lr = wid * 8 + rr;
    const int rg = rows0 + lr;
    const size_t pb = (size_t)(b * 8 + head) * 2048 + (n0 + lr);
    float ox = 0.f, oy = 0.f, l = 0.f;
#pragma unroll
    for (int zz = 0; zz < 4; ++zz) {
      u32 w = *(const u32*)(OpartB + zz * SPLIT_O + pb * 16 + dh);
      ox += __builtin_bit_cast(float, w << 16);
      oy += __builtin_bit_cast(float, w & 0xffff0000u);
      l += __builtin_bit_cast(float, (u32)LpartB[zz * SPLIT_L + pb] << 16);
    }
    float inv = (l > 0.f) ? 1.0f / l : 0.f;
    float2 a = *(const float2*)(qp + (size_t)rg * 128 + lane * 2);
    float x0 = a.x + ox * inv, x1 = a.y + oy * inv;
    float sum = x0 + x1, sq = x0 * x0 + x1 * x1;
#pragma unroll
    for (int off = 1; off < 64; off <<= 1) {
      sum += __shfl_xor(sum, off);
      sq += __shfl_xor(sq, off);
    }
    float mu = sum * (1.f / 128.f);
    float rstd = rsqrtf(sq * (1.f / 128.f) - mu * mu + 1e-6f);
    float y0 = (x0 - mu) * rstd * gg1.x + be1.x;
    float y1 = (x1 - mu) * rstd * gg1.y + be1.y;
    *(float2*)(xfb + (((lr * 512 + lane * 8)) ^ ((lr & 7) << 4))) = make_float2(y0, y1);
    *(u32*)(xb + ((lr * 256 + lane * 4) ^ ((lr & 7) << 4))) =
        (u32)bfr(y0) | ((u32)bfr(y1) << 16);
  }
  __syncthreads();

  // --- phase B: GEMM out1 @ Wo + relu + residual -> Yf ---
  const int g = lane >> 4, c = lane & 15;
  const int wi = wid >> 1, wj = wid & 1;
  f32x4 acc[4];
#pragma unroll
  for (int t = 0; t < 4; ++t) acc[t] = f32x4{0.f, 0.f, 0.f, 0.f};
#pragma unroll
  for (int kk = 0; kk < 4; ++kk) {
    const int row = wi * 16 + c;
    b16x8 af = *(const b16x8*)(xb + ((row * 256 + kk * 64 + g * 16) ^ ((row & 7) << 4)));
#pragma unroll
    for (int t = 0; t < 4; ++t) {
      int col = wj * 64 + t * 16 + c;
      b16x8 bfv = *(const b16x8*)(wb + ((col * 256 + kk * 64 + g * 16) ^ ((col & 7) << 4)));
      acc[t] = mfma16(af, bfv, acc[t]);
    }
  }
#pragma unroll
  for (int t = 0; t < 4; ++t) {
    const int col = wj * 64 + t * 16 + c;
    const float bia = bo[col];
#pragma unroll
    for (int r = 0; r < 4; ++r) {
      const int lr = wi * 16 + g * 4 + r;
      float o1 = *(const float*)(xfb + ((lr * 512 + col * 4) ^ ((lr & 7) << 4)));
      float val = fmaxf(acc[t][r] + bia, 0.f) + o1;
      *(float*)(yfb + ((lr * 512 + col * 4) ^ ((lr & 7) << 4))) = val;
    }
  }
  __syncthreads();

  // --- phase C: LN2 -> out ---
  float2 gg2 = *(const float2*)(g2 + lane * 2);
  float2 be2 = *(const float2*)(b2 + lane * 2);
#pragma unroll
  for (int rr = 0; rr < 8; ++rr) {
    const int lr = wid * 8 + rr;
    float2 a = *(const float2*)(yfb + ((lr * 512 + lane * 8) ^ ((lr & 7) << 4)));
    float x0 = a.x, x1 = a.y;
    float sum = x0 + x1, sq = x0 * x0 + x1 * x1;
#pragma unroll
    for (int off = 1; off < 64; off <<= 1) {
      sum += __shfl_xor(sum, off);
      sq += __shfl_xor(sq, off);
    }
    float mu = sum * (1.f / 128.f);
    float rstd = rsqrtf(sq * (1.f / 128.f) - mu * mu + 1e-6f);
    *(float2*)(out + (size_t)(rows0 + lr) * 128 + lane * 2) =
        make_float2((x0 - mu) * rstd * gg2.x + be2.x, (x1 - mu) * rstd * gg2.y + be2.y);
  }
}

// ---------------------------------------------------------------------------
extern "C" void kernel_launch(void* const* d_in, const int* in_sizes, int n_in,
                              void* d_out, int out_size, void* d_ws, size_t ws_size,
                              hipStream_t stream) {
  const float* q = (const float*)d_in[0];
  const float* k = (const float*)d_in[1];
  const float* v = (const float*)d_in[2];
  const int* mask = (const int*)d_in[3];
  const float* Wq = (const float*)d_in[4];
  const float* bq = (const float*)d_in[5];
  const float* Wk = (const float*)d_in[6];
  const float* bk = (const float*)d_in[7];
  const float* Wv = (const float*)d_in[8];
  const float* bv = (const float*)d_in[9];
  const float* Wo = (const float*)d_in[10];
  const float* bo = (const float*)d_in[11];
  const float* g1 = (const float*)d_in[12];
  const float* b1 = (const float*)d_in[13];
  const float* g2 = (const float*)d_in[14];
  const float* b2 = (const float*)d_in[15];

  // ws layout (~18.6 MiB high-water):
  char* ws = (char*)d_ws;
  float* qp = (float*)(ws + (0ull << 20));       // 0-4 MiB fp32 [8192][128]
  u16* q_bf = (u16*)(ws + (4ull << 20));         // 4-6 MiB [bh][n][16]
  u16* k_bf = (u16*)(ws + (6ull << 20));         // 6-8 MiB [bh][n][16]
  u16* vt = (u16*)(ws + (8ull << 20));           // 8-10 MiB [bh][16][2048] (masked-zeroed)
  u16* OpartB = (u16*)(ws + (10ull << 20));      // 10-18 MiB [4][32][2048][16] bf16
  u16* LpartB = (u16*)(ws + (18ull << 20));      // 18-18.5 MiB [4][32][2048] bf16
  u16* m01 = (u16*)(ws + (18ull << 20) + (1ull << 19));  // 18.5+ [B][2048] bf16 0/1

  k_proj<<<dim3(64, 3), 256, 0, stream>>>(q, k, v, Wq, Wk, Wv, bq, bk, bv,
                                          mask, m01, qp, q_bf, k_bf, vt);
  k_attn7<<<dim3(16, 32, 4), 256, 0, stream>>>(q_bf, k_bf, vt, m01, OpartB, LpartB);
  k_tail<<<256, 256, 0, stream>>>(qp, OpartB, LpartB, g1, b1, Wo, bo, g2, b2,
                                  (float*)d_out);
}

// Round 9
// 52.241 us; speedup vs baseline: 1.0988x; 1.0624x over previous
//
#include <hip/hip_runtime.h>

#define DEV __device__ __forceinline__

typedef unsigned short u16;
typedef unsigned int u32;
typedef float f32x4 __attribute__((ext_vector_type(4)));
typedef float f32x16 __attribute__((ext_vector_type(16)));
typedef __bf16 b16x8 __attribute__((ext_vector_type(8)));
typedef u16 u16x8 __attribute__((ext_vector_type(8)));
typedef u16 u16x4 __attribute__((ext_vector_type(4)));
typedef u32 u32x4 __attribute__((ext_vector_type(4)));

// 1/sqrt(D) * log2(e): QK^T logits directly in log2 units (exp -> v_exp_f32)
#define QSCALE (0.08838834764831845f * 1.44269504089f)

DEV u16 bfr(float x) {  // fp32 -> bf16 RNE
  u32 u = __builtin_bit_cast(u32, x);
  u32 r = u + 0x7fffu + ((u >> 16) & 1u);
  return (u16)(r >> 16);
}

DEV f32x4 mfma16(b16x8 a, b16x8 b, f32x4 c) {
  return __builtin_amdgcn_mfma_f32_16x16x32_bf16(a, b, c, 0, 0, 0);
}

DEV void plswap(u32& a, u32& b) {  // a' = [a.lo32lanes, b.lo32lanes]; b' = [a.hi, b.hi]
  asm volatile("v_permlane32_swap_b32 %0, %1" : "+v"(a), "+v"(b));
}

DEV float fexp2(float x) {  // raw v_exp_f32: 2^x, no libm legalization
  float r;
  asm("v_exp_f32 %0, %1" : "=v"(r) : "v"(x));
  return r;
}

DEV void gll16(const void* g, void* l) {
  __builtin_amdgcn_global_load_lds((const __attribute__((address_space(1))) u32*)g,
                                   (__attribute__((address_space(3))) u32*)l, 16, 0, 0);
}
DEV void gll4(const void* g, void* l) {
  __builtin_amdgcn_global_load_lds((const __attribute__((address_space(1))) u32*)g,
                                   (__attribute__((address_space(3))) u32*)l, 4, 0, 0);
}

// ---------------------------------------------------------------------------
// K1: fused QKV projection + mask->bf16 0/1 conversion.  grid (64, 3).
// mode 0: qp fp32 + q_bf (pre-scaled by QSCALE) [+ mask01 conv on blocks <32];
// mode 1: k_bf; mode 2: vt (transposed, V rows of masked keys zeroed).
// launch_bounds(256,2): 256-VGPR budget -> no AGPR shuffling in GEMM core.
// ---------------------------------------------------------------------------
__global__ __launch_bounds__(256, 2) void k_proj(
    const float* __restrict__ Xq, const float* __restrict__ Xk, const float* __restrict__ Xv,
    const float* __restrict__ Wq, const float* __restrict__ Wk, const float* __restrict__ Wv,
    const float* __restrict__ bq, const float* __restrict__ bk, const float* __restrict__ bv,
    const int* __restrict__ mask, u16* __restrict__ m01,
    float* __restrict__ qp, u16* __restrict__ q_bf, u16* __restrict__ k_bf,
    u16* __restrict__ vt) {
  __shared__ __align__(16) u16 Xs[128 * 128];
  __shared__ __align__(16) u16 Ws[128 * 128];
  const int tid = threadIdx.x;
  const int mode = blockIdx.y;
  const float* X = (mode == 0) ? Xq : (mode == 1 ? Xk : Xv);
  const float* W = (mode == 0) ? Wq : (mode == 1 ? Wk : Wv);
  const float* bias = (mode == 0) ? bq : (mode == 1 ? bk : bv);
  const int row0 = blockIdx.x * 128;
  char* xb = (char*)Xs;
  char* wb = (char*)Ws;

  if (mode == 0 && blockIdx.x < 32) {  // mask -> bf16 0/1
    int i = blockIdx.x * 256 + tid;
    m01[i] = mask[i] ? 0x3F80 : 0;
  }

#pragma unroll
  for (int i = 0; i < 8; ++i) {
    int s = tid + i * 256;
    int row = s >> 4;
    int c0 = (s & 15) * 8;
    const float* src = X + (size_t)(row0 + row) * 128 + c0;
    float4 f0 = *(const float4*)src;
    float4 f1 = *(const float4*)(src + 4);
    u16x8 hv;
    hv[0] = bfr(f0.x); hv[1] = bfr(f0.y); hv[2] = bfr(f0.z); hv[3] = bfr(f0.w);
    hv[4] = bfr(f1.x); hv[5] = bfr(f1.y); hv[6] = bfr(f1.z); hv[7] = bfr(f1.w);
    *(u16x8*)(xb + ((s * 16) ^ ((row & 7) << 4))) = hv;
  }
#pragma unroll
  for (int i = 0; i < 16; ++i) {
    int vecid = i * 256 + tid;
    int kk = vecid >> 5;
    int n0 = (vecid & 31) * 4;
    float4 f = *(const float4*)(W + (size_t)kk * 128 + n0);
    float ff[4] = {f.x, f.y, f.z, f.w};
#pragma unroll
    for (int j = 0; j < 4; ++j) {
      int n = n0 + j;
      *(u16*)(wb + ((n * 256 + kk * 2) ^ ((n & 7) << 4))) = bfr(ff[j]);
    }
  }
  __syncthreads();

  const int lane = tid & 63, wid = tid >> 6;
  const int g = lane >> 4, c = lane & 15;
  const int wi = wid >> 1, wj = wid & 1;

  f32x4 acc[4][4];
#pragma unroll
  for (int a = 0; a < 4; ++a)
#pragma unroll
    for (int b2 = 0; b2 < 4; ++b2) acc[a][b2] = f32x4{0.f, 0.f, 0.f, 0.f};

#pragma unroll
  for (int kk = 0; kk < 4; ++kk) {
    b16x8 af[4], bfv[4];
#pragma unroll
    for (int t = 0; t < 4; ++t) {
      int row = wi * 64 + t * 16 + c;
      af[t] = *(const b16x8*)(xb + ((row * 256 + kk * 64 + g * 16) ^ ((row & 7) << 4)));
      int col = wj * 64 + t * 16 + c;
      bfv[t] = *(const b16x8*)(wb + ((col * 256 + kk * 64 + g * 16) ^ ((col & 7) << 4)));
    }
#pragma unroll
    for (int ti = 0; ti < 4; ++ti)
#pragma unroll
      for (int tj = 0; tj < 4; ++tj) acc[ti][tj] = mfma16(af[ti], bfv[tj], acc[ti][tj]);
  }

#pragma unroll
  for (int tj = 0; tj < 4; ++tj) {
    int col = wj * 64 + tj * 16 + c;
    float bia = bias[col];
    int h = col >> 4, dh = col & 15;
#pragma unroll
    for (int ti = 0; ti < 4; ++ti) {
      int nbase = row0 + wi * 64 + ti * 16 + g * 4;
      f32x4 v4 = acc[ti][tj];
      if (mode == 2) {
        // zero masked keys' V: mask folded into PV + l-weights (exact)
        int bb2 = nbase >> 11, n = nbase & 2047;
        u16x4 pk;
#pragma unroll
        for (int r = 0; r < 4; ++r) {
          float mm = mask[bb2 * 2048 + n + r] ? 1.f : 0.f;
          pk[r] = bfr((v4[r] + bia) * mm);
        }
        *(u16x4*)(vt + ((((size_t)bb2 * 8 + h) * 16 + dh) << 11) + n) = pk;
      } else {
        u16* dst = (mode == 0) ? q_bf : k_bf;
        float sc = (mode == 0) ? QSCALE : 1.0f;
#pragma unroll
        for (int r = 0; r < 4; ++r) {
          int rowg = nbase + r;
          float val = v4[r] + bia;
          if (mode == 0) qp[(size_t)rowg * 128 + col] = val;
          int bb2 = rowg >> 11, n = rowg & 2047;
          dst[((((size_t)bb2 * 8 + h) * 2048 + n) << 4) + dh] = bfr(val * sc);
        }
      }
    }
  }
}

// ---------------------------------------------------------------------------
// K2: flash attention, swapped-QK 32x32x16, mask-free inner loop (mask is
// baked into V + the l-weight row), MFMA row-sum.  grid (16, 32, SPLIT=4),
// 256 threads (4 waves x 32 q-rows).
// launch_bounds(256,2): 256-VGPR budget so st/p/oacc/w stay in arch VGPRs
// (no v_accvgpr read/write shuffling -> ~4x fewer VALU issues per subtile).
// ---------------------------------------------------------------------------
__global__ __launch_bounds__(256, 2) void k_attn7(
    const u16* __restrict__ q_bf, const u16* __restrict__ k_bf,
    const u16* __restrict__ vt, const u16* __restrict__ m01,
    u16* __restrict__ OpartB, u16* __restrict__ LpartB) {
  __shared__ __align__(16) u16 Ks[2][128 * 16];    // [slot sigma] (16B slots)
  __shared__ __align__(16) u16 Vs[2][17 * 128];    // [dh][k] swizzled; row16 = mask01
  const int tid = threadIdx.x, lane = tid & 63, wid = tid >> 6;
  const int q = lane & 31, h = lane >> 5;
  const int bh = blockIdx.y, b = bh >> 3;
  const int z = blockIdx.z;
  const int q0 = blockIdx.x * 128 + wid * 32;

  const u16* Kg = k_bf + (size_t)bh * 2048 * 16;
  const u16* Vg = vt + (size_t)bh * 16 * 2048;
  const u16* M01g = m01 + (size_t)b * 2048;

  // Q B-fragment (col=q, k=dh): in regs all kernel
  b16x8 qf = *(const b16x8*)(q_bf + (((size_t)bh * 2048 + q0 + q) << 4) + h * 8);

  f32x16 oacc = {};
  const f32x16 fzero = {};

  auto stage = [&](int bufi, int ct2) {
    const int kt0 = ct2 * 128;
    // K: dest slot t linear; source slot sigma(t) (involution) -> swizzled LDS
    {
      const int t = wid * 64 + lane;
      const int ssrc = t ^ ((t >> 3) & 7);
      gll16(Kg + (size_t)kt0 * 16 + ssrc * 8, &Ks[bufi][wid * 512]);
    }
    {
      const int dhs = wid * 4 + (lane >> 4);
      const int ts = (lane & 15) ^ (dhs & 7);
      gll16(Vg + (size_t)dhs * 2048 + kt0 + ts * 8, &Vs[bufi][wid * 512]);
    }
    // l-weight row (row 16, unswizzled): mask01 for these 128 keys (256B)
    if (wid == 0) gll4(M01g + kt0 + lane * 2, &Vs[bufi][16 * 128]);
  };

  const int ct0 = z * 4;
  stage(0, ct0);
  const int dhc = (q < 16) ? q : 16;  // V col: dh, clamped to mask01 row

  for (int ct = ct0; ct < ct0 + 4; ++ct) {
    const int cur = ct & 1;
    __syncthreads();
    if (ct < ct0 + 3) stage(cur ^ 1, ct + 1);
    const char* ksb = (const char*)Ks[cur];
    const char* vsb = (const char*)Vs[cur];

#pragma unroll
    for (int kt = 0; kt < 4; ++kt) {
      // K A-fragment from sigma-swizzled slots
      const int s = kt * 64 + q * 2 + h;
      const int srd = s ^ ((s >> 3) & 7);
      b16x8 kf = *(const b16x8*)(ksb + srd * 16);

      // S^T = mfma(A=K, B=Q, C=0); lane: col=q, rows=keys
      f32x16 st = __builtin_amdgcn_mfma_f32_32x32x16_bf16(kf, qf, fzero, 0, 0, 0);

      // unmasked softmax numerator: p = 2^st (mask lives in V / l-weights)
      float p[16];
#pragma unroll
      for (int r = 0; r < 16; ++r) p[r] = fexp2(st[r]);

      // T12: P -> bf16 PV A-fragments in-register
      u32 w[8];
#pragma unroll
      for (int i = 0; i < 8; ++i)
        asm("v_cvt_pk_bf16_f32 %0, %1, %2" : "=v"(w[i]) : "v"(p[2 * i]), "v"(p[2 * i + 1]));
      plswap(w[0], w[2]); plswap(w[1], w[3]);
      plswap(w[4], w[6]); plswap(w[5], w[7]);
      u32x4 f0v = {w[0], w[1], w[2], w[3]};
      u32x4 f1v = {w[4], w[5], w[6], w[7]};
      b16x8 F0 = __builtin_bit_cast(b16x8, f0v);
      b16x8 F1 = __builtin_bit_cast(b16x8, f1v);

      // V B-fragments (col=dh, or mask01 row for q>=16), swizzled slots
      const int t0 = (kt * 4 + h) ^ (dhc & 7);
      const int t1 = (kt * 4 + 2 + h) ^ (dhc & 7);
      b16x8 vf0 = *(const b16x8*)(vsb + (dhc * 16 + t0) * 16);
      b16x8 vf1 = *(const b16x8*)(vsb + (dhc * 16 + t1) * 16);
      oacc = __builtin_amdgcn_mfma_f32_32x32x16_bf16(F0, vf0, oacc, 0, 0, 0);
      oacc = __builtin_amdgcn_mfma_f32_32x32x16_bf16(F1, vf1, oacc, 0, 0, 0);
    }
  }

  // epilogue: cols 0-15 = un-normalized O (bf16); col 16 = l (bf16)
  const size_t rowbase = (size_t)(z * 32 + bh) * 2048 + q0;
  if (q < 16) {
    u16* op = OpartB + rowbase * 16 + q;
#pragma unroll
    for (int g2 = 0; g2 < 4; ++g2)
#pragma unroll
      for (int j = 0; j < 4; ++j) {
        int row = j + 8 * g2 + 4 * h;
        op[(size_t)row * 16] = bfr(oacc[g2 * 4 + j]);
      }
  } else if (q == 16) {
    u16* lp = LpartB + rowbase;
#pragma unroll
    for (int r = 0; r < 16; ++r) {
      int row = (r & 3) + 8 * (r >> 2) + 4 * h;
      lp[row] = bfr(oacc[r]);
    }
  }
}

// ---------------------------------------------------------------------------
// K3: fused tail: combine 4 partials + LN1 -> MLP GEMM -> relu+res -> LN2.
// grid 256 blocks x 32 rows, 256 threads (4 waves).  LDS 72KB -> 2 blk/CU.
// ---------------------------------------------------------------------------
__global__ __launch_bounds__(256, 2) void k_tail(
    const float* __restrict__ qp, const u16* __restrict__ OpartB,
    const u16* __restrict__ LpartB,
    const float* __restrict__ g1, const float* __restrict__ b1,
    const float* __restrict__ Wo, const float* __restrict__ bo,
    const float* __restrict__ g2, const float* __restrict__ b2,
    float* __restrict__ out) {
  __shared__ __align__(16) u16 Ws[128 * 128];   // Wo^T bf16 swizzled (32KB)
  __shared__ __align__(16) u16 Xs[32 * 128];    // out1 bf16 swizzled (8KB)
  __shared__ __align__(16) float Xf[32 * 128];  // out1 f32, row-XOR (16KB)
  __shared__ __align__(16) float Yf[32 * 128];  // y f32, row-XOR (16KB)
  const int tid = threadIdx.x, lane = tid & 63, wid = tid >> 6;
  char* wb = (char*)Ws;
  char* xb = (char*)Xs;
  char* xfb = (char*)Xf;
  char* yfb = (char*)Yf;
  const int rows0 = blockIdx.x * 32;
  const int b = rows0 >> 11, n0 = rows0 & 2047;

  // --- stage Wo^T bf16 swizzled ---
#pragma unroll
  for (int i = 0; i < 16; ++i) {
    int vecid = i * 256 + tid;
    int kk = vecid >> 5;
    int nn = (vecid & 31) * 4;
    float4 f = *(const float4*)(Wo + (size_t)kk * 128 + nn);
    float ff[4] = {f.x, f.y, f.z, f.w};
#pragma unroll
    for (int j = 0; j < 4; ++j) {
      int n = nn + j;
      *(u16*)(wb + ((n * 256 + kk * 2) ^ ((n & 7) << 4))) = bfr(ff[j]);
    }
  }

  // --- phase A: combine partials + LN1; wave wid owns rows wid*8..+7 ---
  const int head = lane >> 3, dh = (lane & 7) * 2;
  const size_t SPLIT_O = (size_t)32 * 2048 * 16;
  const size_t SPLIT_L = (size_t)32 * 2048;
  float2 gg1 = *(const float2*)(g1 + lane * 2);
  float2 be1 = *(const float2*)(b1 + lane * 2);
#pragma unroll
  for (int rr = 0; rr < 8; ++rr) {
    const int lr = wid * 8 + rr;
    const int rg = rows0 + lr;
    const size_t pb = (size_t)(b * 8 + head) * 2048 + (n0 + lr);
    float ox = 0.f, oy = 0.f, l = 0.f;
#pragma unroll
    for (int zz = 0; zz < 4; ++zz) {
      u32 w = *(const u32*)(OpartB + zz * SPLIT_O + pb * 16 + dh);
      ox += __builtin_bit_cast(float, w << 16);
      oy += __builtin_bit_cast(float, w & 0xffff0000u);
      l += __builtin_bit_cast(float, (u32)LpartB[zz * SPLIT_L + pb] << 16);
    }
    float inv = (l > 0.f) ? 1.0f / l : 0.f;
    float2 a = *(const float2*)(qp + (size_t)rg * 128 + lane * 2);
    float x0 = a.x + ox * inv, x1 = a.y + oy * inv;
    float sum = x0 + x1, sq = x0 * x0 + x1 * x1;
#pragma unroll
    for (int off = 1; off < 64; off <<= 1) {
      sum += __shfl_xor(sum, off);
      sq += __shfl_xor(sq, off);
    }
    float mu = sum * (1.f / 128.f);
    float rstd = rsqrtf(sq * (1.f / 128.f) - mu * mu + 1e-6f);
    float y0 = (x0 - mu) * rstd * gg1.x + be1.x;
    float y1 = (x1 - mu) * rstd * gg1.y + be1.y;
    *(float2*)(xfb + (((lr * 512 + lane * 8)) ^ ((lr & 7) << 4))) = make_float2(y0, y1);
    *(u32*)(xb + ((lr * 256 + lane * 4) ^ ((lr & 7) << 4))) =
        (u32)bfr(y0) | ((u32)bfr(y1) << 16);
  }
  __syncthreads();

  // --- phase B: GEMM out1 @ Wo + relu + residual -> Yf ---
  const int g = lane >> 4, c = lane & 15;
  const int wi = wid >> 1, wj = wid & 1;
  f32x4 acc[4];
#pragma unroll
  for (int t = 0; t < 4; ++t) acc[t] = f32x4{0.f, 0.f, 0.f, 0.f};
#pragma unroll
  for (int kk = 0; kk < 4; ++kk) {
    const int row = wi * 16 + c;
    b16x8 af = *(const b16x8*)(xb + ((row * 256 + kk * 64 + g * 16) ^ ((row & 7) << 4)));
#pragma unroll
    for (int t = 0; t < 4; ++t) {
      int col = wj * 64 + t * 16 + c;
      b16x8 bfv = *(const b16x8*)(wb + ((col * 256 + kk * 64 + g * 16) ^ ((col & 7) << 4)));
      acc[t] = mfma16(af, bfv, acc[t]);
    }
  }
#pragma unroll
  for (int t = 0; t < 4; ++t) {
    const int col = wj * 64 + t * 16 + c;
    const float bia = bo[col];
#pragma unroll
    for (int r = 0; r < 4; ++r) {
      const int lr = wi * 16 + g * 4 + r;
      float o1 = *(const float*)(xfb + ((lr * 512 + col * 4) ^ ((lr & 7) << 4)));
      float val = fmaxf(acc[t][r] + bia, 0.f) + o1;
      *(float*)(yfb + ((lr * 512 + col * 4) ^ ((lr & 7) << 4))) = val;
    }
  }
  __syncthreads();

  // --- phase C: LN2 -> out ---
  float2 gg2 = *(const float2*)(g2 + lane * 2);
  float2 be2 = *(const float2*)(b2 + lane * 2);
#pragma unroll
  for (int rr = 0; rr < 8; ++rr) {
    const int lr = wid * 8 + rr;
    float2 a = *(const float2*)(yfb + ((lr * 512 + lane * 8) ^ ((lr & 7) << 4)));
    float x0 = a.x, x1 = a.y;
    float sum = x0 + x1, sq = x0 * x0 + x1 * x1;
#pragma unroll
    for (int off = 1; off < 64; off <<= 1) {
      sum += __shfl_xor(sum, off);
      sq += __shfl_xor(sq, off);
    }
    float mu = sum * (1.f / 128.f);
    float rstd = rsqrtf(sq * (1.f / 128.f) - mu * mu + 1e-6f);
    *(float2*)(out + (size_t)(rows0 + lr) * 128 + lane * 2) =
        make_float2((x0 - mu) * rstd * gg2.x + be2.x, (x1 - mu) * rstd * gg2.y + be2.y);
  }
}

// ---------------------------------------------------------------------------
extern "C" void kernel_launch(void* const* d_in, const int* in_sizes, int n_in,
                              void* d_out, int out_size, void* d_ws, size_t ws_size,
                              hipStream_t stream) {
  const float* q = (const float*)d_in[0];
  const float* k = (const float*)d_in[1];
  const float* v = (const float*)d_in[2];
  const int* mask = (const int*)d_in[3];
  const float* Wq = (const float*)d_in[4];
  const float* bq = (const float*)d_in[5];
  const float* Wk = (const float*)d_in[6];
  const float* bk = (const float*)d_in[7];
  const float* Wv = (const float*)d_in[8];
  const float* bv = (const float*)d_in[9];
  const float* Wo = (const float*)d_in[10];
  const float* bo = (const float*)d_in[11];
  const float* g1 = (const float*)d_in[12];
  const float* b1 = (const float*)d_in[13];
  const float* g2 = (const float*)d_in[14];
  const float* b2 = (const float*)d_in[15];

  // ws layout (~18.6 MiB high-water):
  char* ws = (char*)d_ws;
  float* qp = (float*)(ws + (0ull << 20));       // 0-4 MiB fp32 [8192][128]
  u16* q_bf = (u16*)(ws + (4ull << 20));         // 4-6 MiB [bh][n][16]
  u16* k_bf = (u16*)(ws + (6ull << 20));         // 6-8 MiB [bh][n][16]
  u16* vt = (u16*)(ws + (8ull << 20));           // 8-10 MiB [bh][16][2048] (masked-zeroed)
  u16* OpartB = (u16*)(ws + (10ull << 20));      // 10-18 MiB [4][32][2048][16] bf16
  u16* LpartB = (u16*)(ws + (18ull << 20));      // 18-18.5 MiB [4][32][2048] bf16
  u16* m01 = (u16*)(ws + (18ull << 20) + (1ull << 19));  // 18.5+ [B][2048] bf16 0/1

  k_proj<<<dim3(64, 3), 256, 0, stream>>>(q, k, v, Wq, Wk, Wv, bq, bk, bv,
                                          mask, m01, qp, q_bf, k_bf, vt);
  k_attn7<<<dim3(16, 32, 4), 256, 0, stream>>>(q_bf, k_bf, vt, m01, OpartB, LpartB);
  k_tail<<<256, 256, 0, stream>>>(qp, OpartB, LpartB, g1, b1, Wo, bo, g2, b2,
                                  (float*)d_out);
}